// Round 4
// baseline (2507.288 us; speedup 1.0000x reference)
//
#include <hip/hip_runtime.h>
#include <math.h>

#define Bv 32
#define Tv 256
#define Vv 32000
#define HALF 16000               // floats per half-row
#define NBLK (2 * Bv * Tv)       // 16384 blocks, two per row

__device__ __forceinline__ float exp4(float4 v) {
    return __expf(v.x) + __expf(v.y) + __expf(v.z) + __expf(v.w);
}

// Two blocks per (b,t) row; each sums exp(x) over one half-row (static trip counts).
// Last finishing block performs the fixed-order final reduction (deterministic).
__global__ __launch_bounds__(256) void fused_loss_kernel(const float* __restrict__ pred,
                                                         const int*   __restrict__ gt,
                                                         const int*   __restrict__ lens,
                                                         float*       __restrict__ partial,
                                                         float*       __restrict__ xg,
                                                         unsigned int* __restrict__ counter,
                                                         float*       __restrict__ out) {
    const int bid = blockIdx.x;
    const int r   = bid >> 1;
    const int h   = bid & 1;
    const int b   = r >> 8;              // T = 256
    const int t   = r & 255;
    const int tid = threadIdx.x;

    __shared__ float red[4];
    __shared__ bool  amLast;
    const int wave = tid >> 6;
    const int lane = tid & 63;

    const int tgt_len = lens[b] - 1;
    if (t < tgt_len) {                   // block-uniform branch
        const float4* seg = reinterpret_cast<const float4*>(pred + (size_t)r * Vv + h * HALF);

        // 4000 float4 = 7*512 + 256 + 160, all static bounds -> deep load pipelining
        float s0 = 0.0f, s1 = 0.0f;
        #pragma unroll
        for (int k = 0; k < 7; ++k) {
            float4 a = seg[tid + 512 * k];
            float4 c = seg[tid + 256 + 512 * k];
            s0 += exp4(a);
            s1 += exp4(c);
        }
        { float4 a = seg[tid + 3584]; s0 += exp4(a); }
        if (tid < 160) { float4 a = seg[tid + 3840]; s1 += exp4(a); }
        float s = s0 + s1;

        #pragma unroll
        for (int off = 32; off; off >>= 1) s += __shfl_xor(s, off);
        if (lane == 0) red[wave] = s;
        __syncthreads();
        if (tid == 0) {
            partial[bid] = red[0] + red[1] + red[2] + red[3];
            if (h == 0) xg[r] = pred[(size_t)r * Vv + gt[r]];   // L2 hit
        }
    }

    // ---- completion protocol: release writes, count done blocks ----
    __threadfence();                     // device-scope release of partial/xg
    if (tid == 0) {
        unsigned int old = atomicAdd(counter, 1u);
        amLast = (old == NBLK - 1);
    }
    __syncthreads();
    if (!amLast) return;
    __threadfence();                     // acquire: observe all partials/xg

    // ---- final reduction by the last block, fixed order => deterministic ----
    float s = 0.0f;
    for (int rr = tid; rr < Bv * Tv; rr += 256) {
        const int bb = rr >> 8;
        const int tt = rr & 255;
        if (tt < lens[bb] - 1)
            s += logf(partial[2 * rr] + partial[2 * rr + 1]) - xg[rr];
    }
    #pragma unroll
    for (int off = 32; off; off >>= 1) s += __shfl_xor(s, off);
    if (lane == 0) red[wave] = s;        // red[] reuse: separated by amLast barrier
    __syncthreads();
    if (tid == 0) {
        float ss = red[0] + red[1] + red[2] + red[3];
        long long cnt = 0;
        for (int bb = 0; bb < Bv; ++bb) {
            int c = lens[bb] - 1;
            if (c > 0) cnt += c;
        }
        if (cnt < 1) cnt = 1;
        out[0] = ss / (float)cnt;
    }
}

extern "C" void kernel_launch(void* const* d_in, const int* in_sizes, int n_in,
                              void* d_out, int out_size, void* d_ws, size_t ws_size,
                              hipStream_t stream) {
    const float* pred = (const float*)d_in[0];
    const int*   gt   = (const int*)d_in[1];
    const int*   lens = (const int*)d_in[2];
    float*       out  = (float*)d_out;

    float*        partial = (float*)d_ws;                      // NBLK floats = 64 KiB
    float*        xg      = (float*)d_ws + NBLK;               // B*T floats  = 32 KiB
    unsigned int* counter = (unsigned int*)((char*)d_ws + (NBLK + Bv * Tv) * sizeof(float));

    hipMemsetAsync(counter, 0, sizeof(unsigned int), stream);  // capture-legal
    fused_loss_kernel<<<NBLK, 256, 0, stream>>>(pred, gt, lens, partial, xg, counter, out);
}

// Round 5
// 98.097 us; speedup vs baseline: 25.5593x; 25.5593x over previous
//
#include <hip/hip_runtime.h>
#include <math.h>

#define Bv 32
#define Tv 256
#define Vv 32000
#define QTR 8000                 // floats per quarter-row
#define NBLK (4 * Bv * Tv)       // 32768 blocks, four per row

__device__ __forceinline__ float exp4(float4 v) {
    return __expf(v.x) + __expf(v.y) + __expf(v.z) + __expf(v.w);
}

// Four blocks per (b,t) row; t-major dispatch order so valid rows launch first.
// Each block sums exp(x) over one quarter-row with static trip counts.
__global__ __launch_bounds__(256) void row_partial_kernel(const float* __restrict__ pred,
                                                          const int*   __restrict__ gt,
                                                          const int*   __restrict__ lens,
                                                          float*       __restrict__ partial,
                                                          float*       __restrict__ xg) {
    const int bid = blockIdx.x;          // [0, 4*B*T)
    const int q   = bid & 3;             // quarter
    const int idx = bid >> 2;            // t-major: idx = t*32 + b
    const int t   = idx >> 5;
    const int b   = idx & 31;
    const int r   = (b << 8) | t;        // row in [0, B*T)
    const int tid = threadIdx.x;

    if (t >= lens[b] - 1) return;        // masked row: finalize skips it

    const float4* seg = reinterpret_cast<const float4*>(pred + (size_t)r * Vv + q * QTR);

    // 2000 float4 = 3*512 + 256 + 208, all static bounds -> deep load pipelining
    float s0 = 0.0f, s1 = 0.0f;
    #pragma unroll
    for (int k = 0; k < 3; ++k) {
        float4 a = seg[tid + 512 * k];
        float4 c = seg[tid + 256 + 512 * k];
        s0 += exp4(a);
        s1 += exp4(c);
    }
    { float4 a = seg[tid + 1536]; s0 += exp4(a); }
    if (tid < 208) { float4 a = seg[tid + 1792]; s1 += exp4(a); }
    float s = s0 + s1;

    __shared__ float red[4];
    const int wave = tid >> 6;
    const int lane = tid & 63;
    #pragma unroll
    for (int off = 32; off; off >>= 1) s += __shfl_xor(s, off);
    if (lane == 0) red[wave] = s;
    __syncthreads();
    if (tid == 0) {
        partial[4 * r + q] = red[0] + red[1] + red[2] + red[3];
        if (q == 0) xg[r] = pred[(size_t)r * Vv + gt[r]];   // L2/L3 hit
    }
}

// Single-block deterministic reduction:
//   loss = sum_valid( log(p0+p1+p2+p3) - xg ) / max(sum(max(len-1,0)), 1)
__global__ __launch_bounds__(1024) void finalize_kernel(const float* __restrict__ partial,
                                                        const float* __restrict__ xg,
                                                        const int*   __restrict__ lens,
                                                        float*       __restrict__ out) {
    const int tid = threadIdx.x;
    float s = 0.0f;
    for (int r = tid; r < Bv * Tv; r += 1024) {
        const int b = r >> 8;
        const int t = r & 255;
        if (t < lens[b] - 1) {
            float p = partial[4 * r] + partial[4 * r + 1]
                    + partial[4 * r + 2] + partial[4 * r + 3];
            s += logf(p) - xg[r];
        }
    }

    __shared__ float red[16];
    const int wave = tid >> 6;
    const int lane = tid & 63;
    #pragma unroll
    for (int off = 32; off; off >>= 1) s += __shfl_xor(s, off);
    if (lane == 0) red[wave] = s;
    __syncthreads();
    if (tid == 0) {
        float ss = 0.0f;
        #pragma unroll
        for (int w = 0; w < 16; ++w) ss += red[w];
        long long cnt = 0;
        for (int bb = 0; bb < Bv; ++bb) {
            int c = lens[bb] - 1;
            if (c > 0) cnt += c;
        }
        if (cnt < 1) cnt = 1;
        out[0] = ss / (float)cnt;
    }
}

extern "C" void kernel_launch(void* const* d_in, const int* in_sizes, int n_in,
                              void* d_out, int out_size, void* d_ws, size_t ws_size,
                              hipStream_t stream) {
    const float* pred = (const float*)d_in[0];
    const int*   gt   = (const int*)d_in[1];
    const int*   lens = (const int*)d_in[2];
    float*       out  = (float*)d_out;
    float*       partial = (float*)d_ws;                   // NBLK floats = 128 KiB
    float*       xg      = (float*)d_ws + NBLK;            // B*T floats  =  32 KiB

    row_partial_kernel<<<NBLK, 256, 0, stream>>>(pred, gt, lens, partial, xg);
    finalize_kernel<<<1, 1024, 0, stream>>>(partial, xg, lens, out);
}

// Round 6
// 94.127 us; speedup vs baseline: 26.6374x; 1.0422x over previous
//
#include <hip/hip_runtime.h>
#include <math.h>

#define Bv 32
#define Tv 256
#define Vv 32000
#define HALF 16000        // floats per half-row
#define NV4H 4000         // float4 per half-row

__device__ __forceinline__ float exp4(float4 v) {
    return __expf(v.x) + __expf(v.y) + __expf(v.z) + __expf(v.w);
}

// Two blocks per (b,t) row; each sums exp(x) over one half-row with static trip counts.
// Block h=0 additionally fetches x_gt for the row.
// bid-major: consecutive blocks read contiguous memory (DRAM locality).
__global__ __launch_bounds__(256) void row_partial_kernel(const float* __restrict__ pred,
                                                          const int*   __restrict__ gt,
                                                          const int*   __restrict__ lens,
                                                          float*       __restrict__ partial,
                                                          float*       __restrict__ xg) {
    const int bid = blockIdx.x;          // [0, 2*B*T)
    const int r   = bid >> 1;
    const int h   = bid & 1;
    const int b   = r >> 8;              // T = 256
    const int t   = r & 255;
    const int tid = threadIdx.x;

    const int tgt_len = lens[b] - 1;
    if (t >= tgt_len) return;            // masked row: finalize skips it

    const float4* seg = reinterpret_cast<const float4*>(pred + (size_t)r * Vv + h * HALF);

    // 4000 float4 = 7*512 + 256 + 160, all static bounds -> deep load pipelining
    float s0 = 0.0f, s1 = 0.0f;
    #pragma unroll
    for (int k = 0; k < 7; ++k) {
        float4 a = seg[tid + 512 * k];
        float4 c = seg[tid + 256 + 512 * k];
        s0 += exp4(a);
        s1 += exp4(c);
    }
    {
        float4 a = seg[tid + 3584];
        s0 += exp4(a);
    }
    if (tid < 160) {
        float4 a = seg[tid + 3840];
        s1 += exp4(a);
    }
    float s = s0 + s1;

    __shared__ float red[4];
    const int wave = tid >> 6;
    const int lane = tid & 63;
    #pragma unroll
    for (int off = 32; off; off >>= 1) s += __shfl_xor(s, off);
    if (lane == 0) red[wave] = s;
    __syncthreads();
    if (tid == 0) {
        partial[bid] = red[0] + red[1] + red[2] + red[3];
        if (h == 0) xg[r] = pred[(size_t)r * Vv + gt[r]];
    }
}

// Single-block deterministic reduction:
//   loss = sum_valid( log(p0+p1) - xg ) / max(sum(max(len-1,0)), 1)
__global__ __launch_bounds__(1024) void finalize_kernel(const float* __restrict__ partial,
                                                        const float* __restrict__ xg,
                                                        const int*   __restrict__ lens,
                                                        float*       __restrict__ out) {
    const int tid = threadIdx.x;
    float s = 0.0f;
    for (int r = tid; r < Bv * Tv; r += 1024) {
        const int b = r >> 8;
        const int t = r & 255;
        if (t < lens[b] - 1)
            s += logf(partial[2 * r] + partial[2 * r + 1]) - xg[r];
    }

    __shared__ float red[16];
    const int wave = tid >> 6;
    const int lane = tid & 63;
    #pragma unroll
    for (int off = 32; off; off >>= 1) s += __shfl_xor(s, off);
    if (lane == 0) red[wave] = s;
    __syncthreads();
    if (tid == 0) {
        float ss = 0.0f;
        #pragma unroll
        for (int w = 0; w < 16; ++w) ss += red[w];
        long long cnt = 0;
        for (int bb = 0; bb < Bv; ++bb) {
            int c = lens[bb] - 1;
            if (c > 0) cnt += c;
        }
        if (cnt < 1) cnt = 1;
        out[0] = ss / (float)cnt;
    }
}

extern "C" void kernel_launch(void* const* d_in, const int* in_sizes, int n_in,
                              void* d_out, int out_size, void* d_ws, size_t ws_size,
                              hipStream_t stream) {
    const float* pred = (const float*)d_in[0];
    const int*   gt   = (const int*)d_in[1];
    const int*   lens = (const int*)d_in[2];
    float*       out  = (float*)d_out;
    float*       partial = (float*)d_ws;                   // 2*B*T floats = 64 KiB
    float*       xg      = (float*)d_ws + 2 * Bv * Tv;     // B*T floats   = 32 KiB

    row_partial_kernel<<<2 * Bv * Tv, 256, 0, stream>>>(pred, gt, lens, partial, xg);
    finalize_kernel<<<1, 1024, 0, stream>>>(partial, xg, lens, out);
}